// Round 14
// baseline (448.918 us; speedup 1.0000x reference)
//
#include <hip/hip_runtime.h>
#include <stdint.h>

// Problem constants (fixed by setup_inputs; all tensors f32)
#define B_ROWS 4096
#define D_IN   784
#define H_DIM  800
#define D_OUT  10
#define T_SIM  32
#define N_ELEM (B_ROWS * D_IN)   // 3211264
#define W1T_LD 832               // 800 padded to 52*16 (zero-filled tail)
#define CAP    448               // spiking-list cap/row (mean ~376, sd ~14)

// ---------------------------------------------------------------------------
// Bit-exact JAX threefry2x32 (key = PRNGKey(42) = {0, 42})
// ---------------------------------------------------------------------------
__device__ __forceinline__ void threefry2x32(uint32_t k0, uint32_t k1,
                                             uint32_t& x0, uint32_t& x1) {
  uint32_t ks0 = k0, ks1 = k1, ks2 = k0 ^ k1 ^ 0x1BD11BDAu;
  x0 += ks0; x1 += ks1;
#define TF_RND(r) { x0 += x1; x1 = (x1 << (r)) | (x1 >> (32 - (r))); x1 ^= x0; }
  TF_RND(13) TF_RND(15) TF_RND(26) TF_RND(6)
  x0 += ks1; x1 += ks2 + 1u;
  TF_RND(17) TF_RND(29) TF_RND(16) TF_RND(24)
  x0 += ks2; x1 += ks0 + 2u;
  TF_RND(13) TF_RND(15) TF_RND(26) TF_RND(6)
  x0 += ks0; x1 += ks1 + 3u;
  TF_RND(17) TF_RND(29) TF_RND(16) TF_RND(24)
  x0 += ks1; x1 += ks2 + 4u;
  TF_RND(13) TF_RND(15) TF_RND(26) TF_RND(6)
  x0 += ks2; x1 += ks0 + 5u;
#undef TF_RND
}

// K0a: x_fixed, TRANSPOSED output xfT[k][m] (coalesced both sides via LDS
// tile). Per-element comparison identical to every passing round.
__global__ __launch_bounds__(256) void gen_xfixedT(const float* __restrict__ x,
                                                   float* __restrict__ xfT) {
  __shared__ float tile[16][17];
  const int k0 = blockIdx.x * 16;            // 49 tiles
  const int m0 = blockIdx.y * 16;            // 256 tiles
  const int j = threadIdx.x & 15, i = threadIdx.x >> 4;
  {
    int m = m0 + i, k = k0 + j;
    float xv = x[m * D_IN + k];              // coalesced (j = consecutive k)
    uint32_t c0 = 0u, c1 = (uint32_t)(m * D_IN + k);
    threefry2x32(0u, 42u, c0, c1);
    uint32_t bits = c0 ^ c1;
    float u = __uint_as_float((bits >> 9) | 0x3F800000u) - 1.0f;
    tile[j][i] = (u < xv) ? 1.0f : 0.0f;
  }
  __syncthreads();
  // write: jj = k-offset, ii = m-offset; consecutive tid -> consecutive m
  const int ii = threadIdx.x & 15, jj = threadIdx.x >> 4;
  xfT[(size_t)(k0 + jj) * B_ROWS + m0 + ii] = tile[jj][ii];
}

// K0b: W1T[k][n] = W1[n][k], n padded to 832 with zeros.
__global__ __launch_bounds__(256) void transpose_W1(const float* __restrict__ W1,
                                                    float* __restrict__ W1T) {
  __shared__ float tile[16][17];
  const int k0 = blockIdx.x * 16;            // 49 tiles
  const int n0 = blockIdx.y * 16;            // 52 tiles (832)
  const int j = threadIdx.x & 15, i = threadIdx.x >> 4;
  {
    int n = n0 + i, k = k0 + j;
    tile[j][i] = (n < H_DIM) ? W1[n * D_IN + k] : 0.0f;
  }
  __syncthreads();
  const int ii = threadIdx.x & 15, jj = threadIdx.x >> 4;
  W1T[(size_t)(k0 + jj) * W1T_LD + n0 + ii] = tile[jj][ii];
}

// ---------------------------------------------------------------------------
// K1: cur1 = x_fixed @ W1^T + b1 fused with layer-1 IF periods -> spike-mask
// u32 per neuron. ZERO LDS, ZERO barriers: per k, each lane reads its A-quad
// and B-quad as dwordx4 from global (wave: 16 distinct contiguous 16B each =
// 256 B coalesced, L1/L2-served). Bit-exact: one f32 accumulator per element,
// strictly ascending k, fma chain — identical sequence to all passing rounds.
// ---------------------------------------------------------------------------
__global__ __launch_bounds__(256) void gemm_masks(const float* __restrict__ xfT,
                                                  const float* __restrict__ W1T,
                                                  const float* __restrict__ b1,
                                                  uint32_t* __restrict__ mb) {
  const int t  = threadIdx.x;        // 0..255
  const int tx = t & 15, ty = t >> 4;
  const int m0 = blockIdx.y * 64;
  const int n0 = blockIdx.x * 64;
  const float* aptr = xfT + m0 + ty * 4;     // + k*4096
  const float* bptr = W1T + n0 + tx * 4;     // + k*832 (zero-padded n>=800)

  float acc[4][4] = {};
#pragma unroll 8
  for (int k = 0; k < D_IN; ++k) {           // strict ascending k, single acc
    float4 a4 = *(const float4*)(aptr + (size_t)k * B_ROWS);
    float4 b4 = *(const float4*)(bptr + (size_t)k * W1T_LD);
    float a[4] = {a4.x, a4.y, a4.z, a4.w};
    float b[4] = {b4.x, b4.y, b4.z, b4.w};
#pragma unroll
    for (int mi = 0; mi < 4; mi++)
#pragma unroll
      for (int ni = 0; ni < 4; ni++)
        acc[mi][ni] = __builtin_fmaf(a[mi], b[ni], acc[mi][ni]);
  }
  // Epilogue: + b1 (f32 add like ref), exact f32 IF-period loop, emit mask32
  const int hOut = n0 + tx * 4;
  if (hOut < H_DIM) {
    float4 bb = *(const float4*)&b1[hOut];
#pragma unroll
    for (int mi = 0; mi < 4; mi++) {
      int m = m0 + ty * 4 + mi;
      float c4[4] = {acc[mi][0] + bb.x, acc[mi][1] + bb.y,
                     acc[mi][2] + bb.z, acc[mi][3] + bb.w};
      uint32_t mk4[4];
#pragma unroll
      for (int ni = 0; ni < 4; ni++) {
        float c = c4[ni];
        float v = 0.0f;
        int p = 0;
#pragma unroll 1
        for (int s = 1; s <= T_SIM; s++) {
          float h1 = v + c;                   // f32 add, as reference
          if (h1 >= 1.0f) { p = s; break; }
          v = h1;
        }
        uint32_t mk = 0;
        if (p) for (int s = p; s <= T_SIM; s += p) mk |= 1u << (s - 1);
        mk4[ni] = mk;
      }
      *(uint4*)&mb[(size_t)m * H_DIM + hOut] =
          make_uint4(mk4[0], mk4[1], mk4[2], mk4[3]);
    }
  }
}

// ---------------------------------------------------------------------------
// K2: SNN scan, 1 row/block (37 KB LDS -> 4 blocks/CU, the R9-vs-R13 lesson).
// wave0 ballot-compacts {haddr,mask} ascending-h and self-pads; waves 1-4
// stage W2T concurrently. Exec: wave j, lanes (t, o-parity): 1 b64 broadcast
// (pk) + 1 b32 2-distinct (w) + 3 VALU per entry. 2 barriers total.
// Exactness: per (row,t,o) the ascending-h single-accumulator gated fold —
// never-spiking h skipped (+0 identity), each step +w or +0 (select form;
// pads have mask=0).
// ---------------------------------------------------------------------------
__global__ __launch_bounds__(320) void snn_scan(const uint32_t* __restrict__ mb,
                                                const float* __restrict__ W2,
                                                const float* __restrict__ b2,
                                                float* __restrict__ out) {
  __shared__ __align__(16) float W2T[H_DIM * D_OUT];  // [h][o], 32000 B
  __shared__ __align__(8) uint2 pkS[CAP];             // {h*40, mask}, 3584 B
  __shared__ int      lenS;
  __shared__ float    c2s[T_SIM][D_OUT];
  __shared__ float    b2f[D_OUT];
  const int tid = threadIdx.x;                // 0..319
  const int row = blockIdx.x;

  if (tid < D_OUT) b2f[tid] = b2[tid];

  if (tid < 64) {
    // ---- Build (wave 0): ballot-compact masks, ascending h; self-pad ----
    const int ln = tid;
    const uint64_t lm = (1ull << ln) - 1ull;
    const uint32_t* mrow = mb + (size_t)row * H_DIM;
    uint32_t mv[13];
#pragma unroll
    for (int ch = 0; ch < 13; ++ch) {         // independent coalesced loads
      int h = ch * 64 + ln;
      mv[ch] = (h < H_DIM) ? mrow[h] : 0u;
    }
    int off = 0;
#pragma unroll
    for (int ch = 0; ch < 13; ++ch) {
      bool g = (mv[ch] != 0u);
      uint64_t bal = __ballot(g);
      int pos = off + __popcll(bal & lm);
      if (g && pos < CAP) {
        uint2 pk; pk.x = (uint32_t)((ch * 64 + ln) * 40); pk.y = mv[ch];
        pkS[pos] = pk;
      }
      off += __popcll(bal);
    }
    if (off <= CAP) {                         // self-pad to multiple of 64
      int lp = (off + 63) & ~63;
      int i = off + ln;
      if (i < lp) { pkS[i].x = 0u; pkS[i].y = 0u; }
    }
    if (ln == 0) lenS = off;
  } else {
    // ---- W2T staging (waves 1-4): coalesced read, LDS-scatter write ----
    for (int e = tid - 64; e < H_DIM * D_OUT; e += 256) {
      int o = e / H_DIM, h = e - o * H_DIM;
      W2T[h * D_OUT + o] = W2[e];
    }
  }
  __syncthreads();

  // ---- Exec: wave j, lanes (t, oh); 2 LDS ops + 3 VALU per entry ----
  {
    const int j = tid >> 6;                   // 0..4
    const int lane = tid & 63;
    const int t = lane & 31;
    const int oh = lane >> 5;                 // o = 2j + oh
    const int L = lenS;
    float s = 0.0f;
    if (L <= CAP) {
      const int Lpad = (L + 63) & ~63;
      const char* wbase = (const char*)W2T + 8 * j + 4 * oh;
#pragma unroll 4
      for (int i = 0; i < Lpad; ++i) {
        uint2 pk = pkS[i];                    // b64 broadcast (1 distinct)
        float w = *(const float*)(wbase + pk.x);  // b32, 2-distinct
        bool g = (pk.y >> t) & 1u;
        s += g ? w : 0.0f;                    // identical op to ref (+w / +0)
      }
    } else {                                  // overflow fallback: gated scan
      const uint32_t* mrow = mb + (size_t)row * H_DIM;
      const uint32_t vbit = 1u << t;
      for (int h = 0; h < H_DIM; ++h) {
        uint32_t mk = mrow[h];                // L1 broadcast
        float w = W2T[h * D_OUT + 2 * j + oh];
        s += (mk & vbit) ? w : 0.0f;
      }
    }
    c2s[t][2 * j + oh] = s;
  }
  __syncthreads();

  // ---- Layer-2 IF scan + spike count (exact f32 ref order) ----
  if (tid < D_OUT) {
    const int o = tid;
    const float bb = b2f[o];
    float v = 0.0f; int cnt = 0;
#pragma unroll
    for (int t = 0; t < T_SIM; ++t) {
      float cur2 = c2s[t][o] + bb;            // f32 add of b2, like ref
      float h2 = v + cur2;                    // f32 add
      bool spk = (h2 >= 1.0f);
      cnt += spk ? 1 : 0;
      v = spk ? 0.0f : h2;
    }
    out[(size_t)row * D_OUT + o] = (float)cnt;
  }
}

// ---------------------------------------------------------------------------
extern "C" void kernel_launch(void* const* d_in, const int* in_sizes, int n_in,
                              void* d_out, int out_size, void* d_ws, size_t ws_size,
                              hipStream_t stream) {
  const float* x  = (const float*)d_in[0];
  const float* W1 = (const float*)d_in[1];
  const float* b1 = (const float*)d_in[2];
  const float* W2 = (const float*)d_in[3];
  const float* b2 = (const float*)d_in[4];
  float* outp = (float*)d_out;

  float*    xfT = (float*)d_ws;                         // 12.85 MB
  float*    W1T = xfT + (size_t)D_IN * B_ROWS;          // 784*832*4 = 2.61 MB
  uint32_t* mbuf = (uint32_t*)(W1T + (size_t)D_IN * W1T_LD);  // 13.1 MB

  dim3 g0(D_IN / 16, B_ROWS / 16);                      // 49 x 256
  gen_xfixedT<<<g0, 256, 0, stream>>>(x, xfT);

  dim3 gt(D_IN / 16, W1T_LD / 16);                      // 49 x 52
  transpose_W1<<<gt, 256, 0, stream>>>(W1, W1T);

  dim3 g1(13, B_ROWS / 64);                             // 13 x 64 = 832
  gemm_masks<<<g1, 256, 0, stream>>>(xfT, W1T, b1, mbuf);

  snn_scan<<<B_ROWS, 320, 0, stream>>>(mbuf, W2, b2, outp);
}

// Round 15
// 280.771 us; speedup vs baseline: 1.5989x; 1.5989x over previous
//
#include <hip/hip_runtime.h>
#include <stdint.h>

// Problem constants (fixed by setup_inputs; all tensors f32)
#define B_ROWS 4096
#define D_IN   784
#define H_DIM  800
#define D_OUT  10
#define T_SIM  32
#define N_ELEM (B_ROWS * D_IN)   // 3211264
#define CAP    448               // spiking-list cap/row (mean ~376, sd ~14)

// ---------------------------------------------------------------------------
// Bit-exact JAX threefry2x32 (key = PRNGKey(42) = {0, 42})
// ---------------------------------------------------------------------------
__device__ __forceinline__ void threefry2x32(uint32_t k0, uint32_t k1,
                                             uint32_t& x0, uint32_t& x1) {
  uint32_t ks0 = k0, ks1 = k1, ks2 = k0 ^ k1 ^ 0x1BD11BDAu;
  x0 += ks0; x1 += ks1;
#define TF_RND(r) { x0 += x1; x1 = (x1 << (r)) | (x1 >> (32 - (r))); x1 ^= x0; }
  TF_RND(13) TF_RND(15) TF_RND(26) TF_RND(6)
  x0 += ks1; x1 += ks2 + 1u;
  TF_RND(17) TF_RND(29) TF_RND(16) TF_RND(24)
  x0 += ks2; x1 += ks0 + 2u;
  TF_RND(13) TF_RND(15) TF_RND(26) TF_RND(6)
  x0 += ks0; x1 += ks1 + 3u;
  TF_RND(17) TF_RND(29) TF_RND(16) TF_RND(24)
  x0 += ks1; x1 += ks2 + 4u;
  TF_RND(13) TF_RND(15) TF_RND(26) TF_RND(6)
  x0 += ks2; x1 += ks0 + 5u;
#undef TF_RND
}

// K0 (R13 verbatim): x_fixed[i] = (u[i] < x[i]) ? 1 : 0.
__global__ __launch_bounds__(256) void gen_xfixed(const float* __restrict__ x,
                                                  float* __restrict__ xf) {
  int i = blockIdx.x * blockDim.x + threadIdx.x;
  if (i >= N_ELEM) return;
  uint32_t c0 = 0u, c1 = (uint32_t)i;
  threefry2x32(0u, 42u, c0, c1);
  uint32_t bits = c0 ^ c1;
  float u = __uint_as_float((bits >> 9) | 0x3F800000u) - 1.0f;
  xf[i] = (u < x[i]) ? 1.0f : 0.0f;
}

// ---------------------------------------------------------------------------
// K1 (R13 GEMM verbatim — measured 131 us) + mask-emitting epilogue.
// Bit-exact f32 ascending-k single-accumulator fma chain; period loop is the
// identical f32 add chain to the reference scan; mask = multiples of p.
// ---------------------------------------------------------------------------
#define BM 64
#define BN 64
#define BK 16

__global__ __launch_bounds__(256) void gemm_masks(const float* __restrict__ xf,
                                                  const float* __restrict__ W1,
                                                  const float* __restrict__ b1,
                                                  uint32_t* __restrict__ mb) {
  __shared__ __align__(16) float As[BK][BM + 4];   // stride 272B (16B mult)
  __shared__ __align__(16) float Bs[BK][BN + 4];
  const int m0 = blockIdx.y * BM;
  const int n0 = blockIdx.x * BN;
  const int t  = threadIdx.x;        // 0..255
  const int tx = t & 15, ty = t >> 4;
  const int sM = t >> 2;             // 0..63 staging row
  const int sK = (t & 3) * 4;        // 0,4,8,12
  const int hB = n0 + sM;
  const bool bOK = (hB < H_DIM);
  const float* aptr = xf + (m0 + sM) * D_IN + sK;
  const float* bptr = W1 + (bOK ? hB : 0) * D_IN + sK;

  float4 a4 = *(const float4*)(aptr);
  float4 b4 = *(const float4*)(bptr);
  if (!bOK) { b4.x = b4.y = b4.z = b4.w = 0.0f; }

  float acc[4][4] = {};
  for (int kt = 0; kt < D_IN; kt += BK) {   // 784 = 49*16, ascending k
    As[sK + 0][sM] = a4.x; As[sK + 1][sM] = a4.y;
    As[sK + 2][sM] = a4.z; As[sK + 3][sM] = a4.w;
    Bs[sK + 0][sM] = b4.x; Bs[sK + 1][sM] = b4.y;
    Bs[sK + 2][sM] = b4.z; Bs[sK + 3][sM] = b4.w;
    __syncthreads();
    if (kt + BK < D_IN) {                   // prefetch next tile
      a4 = *(const float4*)(aptr + kt + BK);
      b4 = *(const float4*)(bptr + kt + BK);
      if (!bOK) { b4.x = b4.y = b4.z = b4.w = 0.0f; }
    }
#pragma unroll
    for (int kk = 0; kk < BK; kk++) {       // strict ascending k, single acc
      float4 av = *(const float4*)&As[kk][ty * 4];   // ds_read_b128
      float4 bv = *(const float4*)&Bs[kk][tx * 4];   // ds_read_b128
      float a[4] = {av.x, av.y, av.z, av.w};
      float b[4] = {bv.x, bv.y, bv.z, bv.w};
#pragma unroll
      for (int mi = 0; mi < 4; mi++)
#pragma unroll
        for (int ni = 0; ni < 4; ni++)
          acc[mi][ni] = __builtin_fmaf(a[mi], b[ni], acc[mi][ni]);
    }
    __syncthreads();
  }
  // Epilogue: + b1 (f32 add like ref), exact f32 IF-period loop, emit mask32
  const int hOut = n0 + tx * 4;              // multiple of 4
  if (hOut < H_DIM) {
    float4 bb = *(const float4*)&b1[hOut];
#pragma unroll
    for (int mi = 0; mi < 4; mi++) {
      int m = m0 + ty * 4 + mi;
      float c4[4] = {acc[mi][0] + bb.x, acc[mi][1] + bb.y,
                     acc[mi][2] + bb.z, acc[mi][3] + bb.w};
      uint32_t mk4[4];
#pragma unroll
      for (int ni = 0; ni < 4; ni++) {
        float c = c4[ni];
        float v = 0.0f;
        int p = 0;
#pragma unroll 1
        for (int s = 1; s <= T_SIM; s++) {
          float h1 = v + c;                   // f32 add, as reference
          if (h1 >= 1.0f) { p = s; break; }
          v = h1;
        }
        uint32_t mk = 0;
        if (p) for (int s = p; s <= T_SIM; s += p) mk |= 1u << (s - 1);
        mk4[ni] = mk;
      }
      *(uint4*)&mb[(size_t)m * H_DIM + hOut] =
          make_uint4(mk4[0], mk4[1], mk4[2], mk4[3]);
    }
  }
}

// ---------------------------------------------------------------------------
// K2: SNN scan — R13's 2-LDS-op exec at R9's occupancy. 2 rows/block, 320
// threads; LDS = W2T 32000 + pkS 7168 (+small) < 40960 -> 4 blocks/CU; c2s
// is UNIONED into pkS (barrier-protected). Exec per entry: 1 b64 pk read +
// 1 b64 w read (both <=2-distinct, conflict-free) + ~4 VALU.
// Exactness: per (row,t,o) the ascending-h single-accumulator gated fold —
// never-spiking h skipped (+0 identity), each step +w or +0 (select form;
// pads have mask=0). Overflow (>CAP) -> gated full scan, same order.
// ---------------------------------------------------------------------------
__global__ __launch_bounds__(320) void snn_scan(const uint32_t* __restrict__ mb,
                                                const float* __restrict__ W2,
                                                const float* __restrict__ b2,
                                                float* __restrict__ out) {
  __shared__ __align__(16) float W2T[H_DIM * D_OUT];  // [h][o], 32000 B
  __shared__ __align__(16) uint2 pkS[2][CAP];         // {h*40, mask}, 7168 B
  __shared__ int   lenS[2];
  __shared__ float b2f[D_OUT];
  float* c2s = (float*)&pkS[0][0];            // union: [r][t][o], 2560 B
  const int tid  = threadIdx.x;               // 0..319
  const int row0 = blockIdx.x * 2;

  if (tid < D_OUT) b2f[tid] = b2[tid];

  if (tid < 128) {
    // ---- Build (waves 0-1): ballot-compact mask words, ascending h ----
    const int r = tid >> 6, ln = tid & 63;
    const uint64_t lm = (1ull << ln) - 1ull;
    const uint32_t* mrow = mb + (size_t)(row0 + r) * H_DIM;
    uint32_t mv[13];
#pragma unroll
    for (int ch = 0; ch < 13; ++ch) {         // independent coalesced loads
      int h = ch * 64 + ln;
      mv[ch] = (h < H_DIM) ? mrow[h] : 0u;
    }
    int off = 0;
#pragma unroll
    for (int ch = 0; ch < 13; ++ch) {
      bool g = (mv[ch] != 0u);
      uint64_t bal = __ballot(g);
      int pos = off + __popcll(bal & lm);
      if (g && pos < CAP) {
        uint2 pk; pk.x = (uint32_t)((ch * 64 + ln) * 40); pk.y = mv[ch];
        pkS[r][pos] = pk;
      }
      off += __popcll(bal);
    }
    if (off <= CAP) {                         // self-pad to multiple of 64
      int lp = (off + 63) & ~63;              // <= CAP since off <= CAP
      int i = off + ln;
      if (i < lp) { pkS[r][i].x = 0u; pkS[r][i].y = 0u; }
    }
    if (ln == 0) lenS[r] = off;
  } else {
    // ---- W2T staging (waves 2-4): coalesced read, LDS scatter ----
    for (int e = tid - 128; e < H_DIM * D_OUT; e += 192) {
      int o = e / H_DIM, h = e - o * H_DIM;
      W2T[h * D_OUT + o] = W2[e];
    }
  }
  __syncthreads();

  // ---- Exec: wave j = o-pair, lanes (t, r); 2 LDS ops per entry ----
  float s0 = 0.0f, s1 = 0.0f;
  const int j = tid >> 6;                     // 0..4
  const int lane = tid & 63;
  const int t = lane & 31;
  const int r = lane >> 5;
  const bool ovf = (lenS[0] > CAP) || (lenS[1] > CAP);
  {
    if (!ovf) {
      const int Lpad = (lenS[r] + 63) & ~63;  // per-r trip count (divergent ok)
      const uint2* pp = pkS[r];
      const char* wbase = (const char*)W2T + 8 * j;
#pragma unroll 4
      for (int i = 0; i < Lpad; ++i) {
        uint2 pk = pp[i];                     // b64, 2-distinct broadcast
        float2 w = *(const float2*)(wbase + pk.x);  // b64, 2-distinct
        bool g = (pk.y >> t) & 1u;
        s0 += g ? w.x : 0.0f;                 // identical op to ref (+w / +0)
        s1 += g ? w.y : 0.0f;
      }
    } else {                                  // overflow fallback: gated scan
      const uint32_t* mrow = mb + (size_t)(row0 + r) * H_DIM;
      const uint32_t vbit = 1u << t;
      for (int h = 0; h < H_DIM; ++h) {
        uint32_t mk = mrow[h];
        float2 w = *(const float2*)&W2T[h * D_OUT + 2 * j];
        s0 += (mk & vbit) ? w.x : 0.0f;
        s1 += (mk & vbit) ? w.y : 0.0f;
      }
    }
  }
  __syncthreads();                            // all pk reads complete
  c2s[((r * T_SIM) + t) * D_OUT + 2 * j]     = s0;   // union region write
  c2s[((r * T_SIM) + t) * D_OUT + 2 * j + 1] = s1;
  __syncthreads();

  // ---- Layer-2 IF scan + spike count (exact f32 ref order) ----
  if (tid < 2 * D_OUT) {
    const int rr = tid / D_OUT, o = tid % D_OUT;
    const float bb = b2f[o];
    float v = 0.0f; int cnt = 0;
#pragma unroll
    for (int tt = 0; tt < T_SIM; ++tt) {
      float cur2 = c2s[((rr * T_SIM) + tt) * D_OUT + o] + bb;  // f32 add
      float h2 = v + cur2;                    // f32 add
      bool spk = (h2 >= 1.0f);
      cnt += spk ? 1 : 0;
      v = spk ? 0.0f : h2;
    }
    out[(size_t)(row0 + rr) * D_OUT + o] = (float)cnt;
  }
}

// ---------------------------------------------------------------------------
extern "C" void kernel_launch(void* const* d_in, const int* in_sizes, int n_in,
                              void* d_out, int out_size, void* d_ws, size_t ws_size,
                              hipStream_t stream) {
  const float* x  = (const float*)d_in[0];
  const float* W1 = (const float*)d_in[1];
  const float* b1 = (const float*)d_in[2];
  const float* W2 = (const float*)d_in[3];
  const float* b2 = (const float*)d_in[4];
  float* outp = (float*)d_out;

  float*    xf = (float*)d_ws;                      // N_ELEM f32 (12.85 MB)
  uint32_t* mbuf = (uint32_t*)(xf + N_ELEM);        // B*H u32   (13.1 MB)

  gen_xfixed<<<N_ELEM / 256, 256, 0, stream>>>(x, xf);

  dim3 g1((H_DIM + BN - 1) / BN, B_ROWS / BM);      // 13 x 64 = 832 blocks
  gemm_masks<<<g1, 256, 0, stream>>>(xf, W1, b1, mbuf);

  snn_scan<<<B_ROWS / 2, 320, 0, stream>>>(mbuf, W2, b2, outp);
}